// Round 5
// baseline (60.350 us; speedup 1.0000x reference)
//
#include <hip/hip_runtime.h>

// MutualInformation2D — R5: MEASUREMENT ROUND.
// Real pipeline identical to R4 (hist -> mi -> finalize). Two probe kernels
// added to attribute the invariant ~44us: p_atomic (LDS atomics only) vs
// p_load (global reads only). rocprof per-dispatch durations arbitrate.

#define BINS 32
#define NBINS2 1024
#define LDS_ROW 33                       // padded row stride
#define LDS_HIST (BINS * LDS_ROW)        // 1056
#define NBATCH 32
#define N_PER_BATCH (2 * 512 * 512)      // 524288 floats per batch
#define NVEC_BATCH (N_PER_BATCH / 4)     // 131072 float4 per batch
#define BPB 64                           // blocks per batch
#define THREADS 256
#define VPT 8                            // float4 per thread per array

// ---------- probe A: pure LDS-atomic throughput (no global loads) ----------
__global__ __launch_bounds__(THREADS) void p_atomic_kernel() {
    __shared__ unsigned h[LDS_HIST];
    for (int i = threadIdx.x; i < LDS_HIST; i += THREADS) h[i] = 0u;
    __syncthreads();

    unsigned s = (blockIdx.x * 256u + threadIdx.x) * 2654435761u + 12345u;
#pragma unroll
    for (int i = 0; i < 32; ++i) {
        s = s * 1664525u + 1013904223u;
        unsigned bin = (s >> 7) & 1023u;           // uniform over 1024 bins
        atomicAdd(&h[(bin >> 5) * LDS_ROW + (bin & 31)], 1u);
    }
    __syncthreads();
    unsigned v = h[threadIdx.x];                   // force atomics observable
    asm volatile("" :: "v"(v));
}

// ---------- probe B: pure read path (hist's exact addressing, no LDS) ------
__global__ __launch_bounds__(THREADS) void p_load_kernel(const float* __restrict__ x,
                                                         const float* __restrict__ y) {
    const int b   = blockIdx.x >> 6;
    const int blk = blockIdx.x & 63;
    const float4* xb = (const float4*)x + (size_t)b * NVEC_BATCH;
    const float4* yb = (const float4*)y + (size_t)b * NVEC_BATCH;
    const int off = blk * THREADS + threadIdx.x;

    float4 xa[VPT], ya[VPT];
#pragma unroll
    for (int j = 0; j < VPT; ++j) xa[j] = xb[(size_t)j * (BPB * THREADS) + off];
#pragma unroll
    for (int j = 0; j < VPT; ++j) ya[j] = yb[(size_t)j * (BPB * THREADS) + off];
#pragma unroll
    for (int j = 0; j < VPT; ++j) {
        asm volatile("" :: "v"(xa[j].x), "v"(xa[j].y), "v"(xa[j].z), "v"(xa[j].w));
        asm volatile("" :: "v"(ya[j].x), "v"(ya[j].y), "v"(ya[j].z), "v"(ya[j].w));
    }
}

// ---------------------- real pipeline (identical to R4) --------------------
__global__ __launch_bounds__(THREADS) void hist_kernel(const float* __restrict__ x,
                                                       const float* __restrict__ y,
                                                       unsigned* __restrict__ parts) {
    __shared__ unsigned h[LDS_HIST];
    for (int i = threadIdx.x; i < LDS_HIST; i += THREADS) h[i] = 0u;
    __syncthreads();

    const int b   = blockIdx.x >> 6;
    const int blk = blockIdx.x & 63;
    const float4* xb = (const float4*)x + (size_t)b * NVEC_BATCH;
    const float4* yb = (const float4*)y + (size_t)b * NVEC_BATCH;

    const int off = blk * THREADS + threadIdx.x;
    float4 xa[VPT], ya[VPT];
#pragma unroll
    for (int j = 0; j < VPT; ++j) xa[j] = xb[(size_t)j * (BPB * THREADS) + off];
#pragma unroll
    for (int j = 0; j < VPT; ++j) ya[j] = yb[(size_t)j * (BPB * THREADS) + off];

#pragma unroll
    for (int j = 0; j < VPT; ++j) {
        float ax[4] = {xa[j].x, xa[j].y, xa[j].z, xa[j].w};
        float ty[4] = {ya[j].x, ya[j].y, ya[j].z, ya[j].w};
#pragma unroll
        for (int k = 0; k < 4; ++k) {
            float u = (ax[k] + 1.0f) * 0.5f;
            float v = (ty[k] + 1.0f) * 0.5f;
            bool ok = (u >= 0.0f) & (u <= 1.0f) & (v >= 0.0f) & (v <= 1.0f);
            if (ok) {
                int iu = (int)(u * 32.0f); if (iu > 31) iu = 31;
                int iv = (int)(v * 32.0f); if (iv > 31) iv = 31;
                atomicAdd(&h[iu * LDS_ROW + iv], 1u);
            }
        }
    }
    __syncthreads();

    unsigned* g = parts + (size_t)blockIdx.x * NBINS2;
    for (int i = threadIdx.x; i < NBINS2; i += THREADS)
        g[i] = h[(i >> 5) * LDS_ROW + (i & 31)];
}

__global__ __launch_bounds__(1024) void mi_kernel(const unsigned* __restrict__ parts,
                                                  int nparts,
                                                  double* __restrict__ mi_out) {
    __shared__ unsigned c[NBINS2];
    __shared__ unsigned px[BINS];
    __shared__ unsigned py[BINS];
    __shared__ double red[16];

    const int b = blockIdx.x;
    const unsigned* base = parts + (size_t)b * nparts * NBINS2 + threadIdx.x;
    unsigned s = 0;
#pragma unroll 8
    for (int p = 0; p < nparts; ++p) s += base[(size_t)p * NBINS2];
    c[threadIdx.x] = s;
    __syncthreads();

    if (threadIdx.x < 32) {
        unsigned r = 0;
        for (int j = 0; j < 32; ++j) r += c[threadIdx.x * BINS + j];
        px[threadIdx.x] = r;
    } else if (threadIdx.x < 64) {
        int col = threadIdx.x - 32;
        unsigned r = 0;
        for (int j = 0; j < 32; ++j) r += c[j * BINS + col];
        py[col] = r;
    }
    __syncthreads();

    unsigned total = 0;
    for (int j = 0; j < 32; ++j) total += px[j];
    const double T = (double)total;

    double acc = 0.0;
    {
        unsigned cc = c[threadIdx.x];
        if (cc) {
            int r = threadIdx.x >> 5, col = threadIdx.x & 31;
            acc = (double)cc * log((double)cc * T / ((double)px[r] * (double)py[col]));
        }
    }
    for (int off = 32; off > 0; off >>= 1)
        acc += __shfl_down(acc, off, 64);
    int wave = threadIdx.x >> 6;
    if ((threadIdx.x & 63) == 0) red[wave] = acc;
    __syncthreads();
    if (threadIdx.x == 0) {
        double t = 0.0;
        for (int i = 0; i < 16; ++i) t += red[i];
        mi_out[b] = t / T;
    }
}

__global__ void finalize_kernel(const double* __restrict__ mi, float* __restrict__ out) {
    if (threadIdx.x == 0) {
        double s = 0.0;
        for (int i = 0; i < NBATCH; ++i) s += mi[i];
        out[0] = (float)(-s / (double)NBATCH);
    }
}

extern "C" void kernel_launch(void* const* d_in, const int* in_sizes, int n_in,
                              void* d_out, int out_size, void* d_ws, size_t ws_size,
                              hipStream_t stream) {
    const float* x = (const float*)d_in[0];
    const float* y = (const float*)d_in[1];
    float* out = (float*)d_out;

    unsigned* parts = (unsigned*)d_ws;   // 32*64*1024*4 = 8 MiB
    double* mi = (double*)((char*)d_ws + (size_t)NBATCH * BPB * NBINS2 * sizeof(unsigned));

    // Probes first (write nothing that survives; hist overwrites parts fully).
    p_atomic_kernel<<<NBATCH * BPB, THREADS, 0, stream>>>();
    p_load_kernel<<<NBATCH * BPB, THREADS, 0, stream>>>(x, y);

    hist_kernel<<<NBATCH * BPB, THREADS, 0, stream>>>(x, y, parts);
    mi_kernel<<<NBATCH, 1024, 0, stream>>>(parts, BPB, mi);
    finalize_kernel<<<1, 64, 0, stream>>>(mi, out);
}

// Round 6
// 38.380 us; speedup vs baseline: 1.5724x; 1.5724x over previous
//
#include <hip/hip_runtime.h>

// MutualInformation2D: B=32 batches, N=2*512*512=524288 points/batch.
// R6: R4 structure, single change — non-temporal (nt) input loads.
// Per-block private histograms (plain stores) -> per-batch integer reduction
// + MI in double -> scalar out = -mean(mi).

#define BINS 32
#define NBINS2 1024
#define LDS_ROW 33                       // padded row stride
#define LDS_HIST (BINS * LDS_ROW)        // 1056
#define NBATCH 32
#define N_PER_BATCH (2 * 512 * 512)      // 524288 floats per batch
#define NVEC_BATCH (N_PER_BATCH / 4)     // 131072 float4 per batch
#define BPB 64                           // blocks per batch
#define THREADS 256
#define VPT 8                            // float4 per thread per array

typedef float f32x4 __attribute__((ext_vector_type(4)));

__global__ __launch_bounds__(THREADS) void hist_kernel(const float* __restrict__ x,
                                                       const float* __restrict__ y,
                                                       unsigned* __restrict__ parts) {
    __shared__ unsigned h[LDS_HIST];
    for (int i = threadIdx.x; i < LDS_HIST; i += THREADS) h[i] = 0u;
    __syncthreads();

    const int b   = blockIdx.x >> 6;     // / BPB
    const int blk = blockIdx.x & 63;     // % BPB
    const f32x4* xb = (const f32x4*)x + (size_t)b * NVEC_BATCH;
    const f32x4* yb = (const f32x4*)y + (size_t)b * NVEC_BATCH;

    // Block-cyclic interleave; NT loads: zero-reuse stream, don't allocate
    // in L2/L3 (single nt dwordx4 per f32x4 via ext_vector_type).
    const int off = blk * THREADS + threadIdx.x;
    f32x4 xa[VPT], ya[VPT];
#pragma unroll
    for (int j = 0; j < VPT; ++j)
        xa[j] = __builtin_nontemporal_load(xb + (size_t)j * (BPB * THREADS) + off);
#pragma unroll
    for (int j = 0; j < VPT; ++j)
        ya[j] = __builtin_nontemporal_load(yb + (size_t)j * (BPB * THREADS) + off);

#pragma unroll
    for (int j = 0; j < VPT; ++j) {
#pragma unroll
        for (int k = 0; k < 4; ++k) {
            // Exact float32 replication of the reference binning.
            float u = (xa[j][k] + 1.0f) * 0.5f;
            float v = (ya[j][k] + 1.0f) * 0.5f;
            bool ok = (u >= 0.0f) & (u <= 1.0f) & (v >= 0.0f) & (v <= 1.0f);
            if (ok) {
                int iu = (int)(u * 32.0f); if (iu > 31) iu = 31;
                int iv = (int)(v * 32.0f); if (iv > 31) iv = 31;
                atomicAdd(&h[iu * LDS_ROW + iv], 1u);
            }
        }
    }
    __syncthreads();

    // Plain coalesced stores of the private histogram — no global atomics.
    unsigned* g = parts + (size_t)blockIdx.x * NBINS2;
    for (int i = threadIdx.x; i < NBINS2; i += THREADS)
        g[i] = h[(i >> 5) * LDS_ROW + (i & 31)];
}

__global__ __launch_bounds__(1024) void mi_kernel(const unsigned* __restrict__ parts,
                                                  int nparts,
                                                  double* __restrict__ mi_out) {
    __shared__ unsigned c[NBINS2];
    __shared__ unsigned px[BINS];
    __shared__ unsigned py[BINS];
    __shared__ double red[16];

    const int b = blockIdx.x;
    // Reduce partials: thread i owns bin i. Integer adds -> order-independent.
    const unsigned* base = parts + (size_t)b * nparts * NBINS2 + threadIdx.x;
    unsigned s = 0;
#pragma unroll 8
    for (int p = 0; p < nparts; ++p) s += base[(size_t)p * NBINS2];
    c[threadIdx.x] = s;
    __syncthreads();

    if (threadIdx.x < 32) {
        unsigned r = 0;
        for (int j = 0; j < 32; ++j) r += c[threadIdx.x * BINS + j];
        px[threadIdx.x] = r;
    } else if (threadIdx.x < 64) {
        int col = threadIdx.x - 32;
        unsigned r = 0;
        for (int j = 0; j < 32; ++j) r += c[j * BINS + col];
        py[col] = r;
    }
    __syncthreads();

    unsigned total = 0;
    for (int j = 0; j < 32; ++j) total += px[j];
    const double T = (double)total;

    double acc = 0.0;
    {
        unsigned cc = c[threadIdx.x];
        if (cc) {
            int r = threadIdx.x >> 5, col = threadIdx.x & 31;
            acc = (double)cc * log((double)cc * T / ((double)px[r] * (double)py[col]));
        }
    }
    // wave (64-lane) shuffle reduction, fixed order -> deterministic
    for (int off = 32; off > 0; off >>= 1)
        acc += __shfl_down(acc, off, 64);
    int wave = threadIdx.x >> 6;
    if ((threadIdx.x & 63) == 0) red[wave] = acc;
    __syncthreads();
    if (threadIdx.x == 0) {
        double t = 0.0;
        for (int i = 0; i < 16; ++i) t += red[i];
        mi_out[b] = t / T;
    }
}

__global__ void finalize_kernel(const double* __restrict__ mi, float* __restrict__ out) {
    if (threadIdx.x == 0) {
        double s = 0.0;
        for (int i = 0; i < NBATCH; ++i) s += mi[i];
        out[0] = (float)(-s / (double)NBATCH);
    }
}

extern "C" void kernel_launch(void* const* d_in, const int* in_sizes, int n_in,
                              void* d_out, int out_size, void* d_ws, size_t ws_size,
                              hipStream_t stream) {
    const float* x = (const float*)d_in[0];
    const float* y = (const float*)d_in[1];
    float* out = (float*)d_out;

    unsigned* parts = (unsigned*)d_ws;   // 32*64*1024*4 = 8 MiB
    double* mi = (double*)((char*)d_ws + (size_t)NBATCH * BPB * NBINS2 * sizeof(unsigned));

    hist_kernel<<<NBATCH * BPB, THREADS, 0, stream>>>(x, y, parts);
    mi_kernel<<<NBATCH, 1024, 0, stream>>>(parts, BPB, mi);
    finalize_kernel<<<1, 64, 0, stream>>>(mi, out);
}

// Round 7
// 37.215 us; speedup vs baseline: 1.6217x; 1.0313x over previous
//
#include <hip/hip_runtime.h>

// MutualInformation2D: B=32 batches, N=2*512*512=524288 points/batch.
// R7: plain float4 loads (NT reverted), BPB=16 (2 MiB partials), ping-pong
// tile pipeline to keep loads in flight through the consume phase.
// hist (per-block private, plain stores) -> mi (integer reduce + double MI)
// -> finalize (-mean). No global atomics anywhere -> deterministic.

#define BINS 32
#define NBINS2 1024
#define LDS_ROW 33                       // padded row stride
#define LDS_HIST (BINS * LDS_ROW)        // 1056
#define NBATCH 32
#define N_PER_BATCH (2 * 512 * 512)      // 524288 floats per batch
#define NVEC_BATCH (N_PER_BATCH / 4)     // 131072 float4 per batch
#define BPB 16                           // blocks per batch
#define THREADS 256
#define NTILE 4                          // tiles per thread
#define TV 8                             // float4 per tile per array
// per block: NTILE*TV*THREADS = 8192 float4 per array; *BPB = 131072 ✓

__global__ __launch_bounds__(THREADS) void hist_kernel(const float* __restrict__ x,
                                                       const float* __restrict__ y,
                                                       unsigned* __restrict__ parts) {
    __shared__ unsigned h[LDS_HIST];
    for (int i = threadIdx.x; i < LDS_HIST; i += THREADS) h[i] = 0u;
    __syncthreads();

    const int b   = blockIdx.x / BPB;
    const int blk = blockIdx.x % BPB;
    const float4* xb = (const float4*)x + (size_t)b * NVEC_BATCH;
    const float4* yb = (const float4*)y + (size_t)b * NVEC_BATCH;
    // Block-cyclic interleave over the batch; stride between a tile's loads
    // keeps each wave-load a contiguous 1 KiB line.
    const int off = blk * THREADS + threadIdx.x;
    const int STRIDE = BPB * THREADS;    // 4096 float4

#define LOAD_TILE(XA, YA, T)                                                  \
    _Pragma("unroll")                                                         \
    for (int j = 0; j < TV; ++j)                                              \
        XA[j] = xb[(size_t)((T) * TV + j) * STRIDE + off];                    \
    _Pragma("unroll")                                                         \
    for (int j = 0; j < TV; ++j)                                              \
        YA[j] = yb[(size_t)((T) * TV + j) * STRIDE + off];

#define CONSUME_TILE(XA, YA)                                                  \
    _Pragma("unroll")                                                         \
    for (int j = 0; j < TV; ++j) {                                            \
        float ax[4] = {XA[j].x, XA[j].y, XA[j].z, XA[j].w};                   \
        float ty[4] = {YA[j].x, YA[j].y, YA[j].z, YA[j].w};                   \
        _Pragma("unroll")                                                     \
        for (int k = 0; k < 4; ++k) {                                         \
            float u = (ax[k] + 1.0f) * 0.5f;                                  \
            float v = (ty[k] + 1.0f) * 0.5f;                                  \
            bool ok = (u >= 0.0f) & (u <= 1.0f) & (v >= 0.0f) & (v <= 1.0f);  \
            if (ok) {                                                         \
                int iu = (int)(u * 32.0f); if (iu > 31) iu = 31;              \
                int iv = (int)(v * 32.0f); if (iv > 31) iv = 31;              \
                atomicAdd(&h[iu * LDS_ROW + iv], 1u);                         \
            }                                                                 \
        }                                                                     \
    }

    // Ping-pong pipeline: load t+1 while consuming t (all indices static).
    float4 xA[TV], yA[TV], xB[TV], yB[TV];
    LOAD_TILE(xA, yA, 0)
    LOAD_TILE(xB, yB, 1)
    CONSUME_TILE(xA, yA)
    LOAD_TILE(xA, yA, 2)
    CONSUME_TILE(xB, yB)
    LOAD_TILE(xB, yB, 3)
    CONSUME_TILE(xA, yA)
    CONSUME_TILE(xB, yB)
#undef LOAD_TILE
#undef CONSUME_TILE

    __syncthreads();

    // Plain coalesced stores of the private histogram — no global atomics.
    unsigned* g = parts + (size_t)blockIdx.x * NBINS2;
    for (int i = threadIdx.x; i < NBINS2; i += THREADS)
        g[i] = h[(i >> 5) * LDS_ROW + (i & 31)];
}

__global__ __launch_bounds__(1024) void mi_kernel(const unsigned* __restrict__ parts,
                                                  double* __restrict__ mi_out) {
    __shared__ unsigned c[NBINS2];
    __shared__ unsigned px[BINS];
    __shared__ unsigned py[BINS];
    __shared__ double red[16];

    const int b = blockIdx.x;
    // Reduce partials: thread i owns bin i. Integer adds -> order-independent.
    const unsigned* base = parts + (size_t)b * BPB * NBINS2 + threadIdx.x;
    unsigned s = 0;
#pragma unroll
    for (int p = 0; p < BPB; ++p) s += base[(size_t)p * NBINS2];
    c[threadIdx.x] = s;
    __syncthreads();

    if (threadIdx.x < 32) {
        unsigned r = 0;
        for (int j = 0; j < 32; ++j) r += c[threadIdx.x * BINS + j];
        px[threadIdx.x] = r;
    } else if (threadIdx.x < 64) {
        int col = threadIdx.x - 32;
        unsigned r = 0;
        for (int j = 0; j < 32; ++j) r += c[j * BINS + col];
        py[col] = r;
    }
    __syncthreads();

    unsigned total = 0;
    for (int j = 0; j < 32; ++j) total += px[j];
    const double T = (double)total;

    double acc = 0.0;
    {
        unsigned cc = c[threadIdx.x];
        if (cc) {
            int r = threadIdx.x >> 5, col = threadIdx.x & 31;
            acc = (double)cc * log((double)cc * T / ((double)px[r] * (double)py[col]));
        }
    }
    // wave (64-lane) shuffle reduction, fixed order -> deterministic
    for (int off = 32; off > 0; off >>= 1)
        acc += __shfl_down(acc, off, 64);
    int wave = threadIdx.x >> 6;
    if ((threadIdx.x & 63) == 0) red[wave] = acc;
    __syncthreads();
    if (threadIdx.x == 0) {
        double t = 0.0;
        for (int i = 0; i < 16; ++i) t += red[i];
        mi_out[b] = t / T;
    }
}

__global__ void finalize_kernel(const double* __restrict__ mi, float* __restrict__ out) {
    if (threadIdx.x == 0) {
        double s = 0.0;
        for (int i = 0; i < NBATCH; ++i) s += mi[i];
        out[0] = (float)(-s / (double)NBATCH);
    }
}

extern "C" void kernel_launch(void* const* d_in, const int* in_sizes, int n_in,
                              void* d_out, int out_size, void* d_ws, size_t ws_size,
                              hipStream_t stream) {
    const float* x = (const float*)d_in[0];
    const float* y = (const float*)d_in[1];
    float* out = (float*)d_out;

    unsigned* parts = (unsigned*)d_ws;   // 32*16*1024*4 = 2 MiB
    double* mi = (double*)((char*)d_ws + (size_t)NBATCH * BPB * NBINS2 * sizeof(unsigned));

    hist_kernel<<<NBATCH * BPB, THREADS, 0, stream>>>(x, y, parts);
    mi_kernel<<<NBATCH, 1024, 0, stream>>>(parts, mi);
    finalize_kernel<<<1, 64, 0, stream>>>(mi, out);
}